// Round 1
// baseline (81.638 us; speedup 1.0000x reference)
//
#include <hip/hip_runtime.h>

#define B_ROWS 32768
#define D_DIM  256
#define N_NEUR 256
#define DEG    8
#define F_FEAT (D_DIM * (DEG + 1))  // 2304

// Stage 1: w[f] = sum_n coeffs[n,f] * h[n]
// grid (F/256, N/16), block 256. Coalesced over f; 16 atomics per w-location.
__global__ __launch_bounds__(256) void reduce_w_kernel(
    const float* __restrict__ coeffs, const float* __restrict__ h,
    float* __restrict__ w) {
  int f  = blockIdx.x * 256 + threadIdx.x;
  int n0 = blockIdx.y * 16;
  float acc = 0.f;
#pragma unroll
  for (int j = 0; j < 16; ++j) {
    int n = n0 + j;
    acc = fmaf(coeffs[(size_t)n * F_FEAT + f], h[n], acc);
  }
  atomicAdd(&w[f], acc);
}

// Stage 2: out[b] = sum_d sum_k T_k(tanh(x[b,d])) * w[9d+k]
// One wave per row. Lane l owns dims 4l..4l+3 (one dwordx4 x-load per row).
// Per-lane 36 w coeffs live in registers, loaded once per block.
__global__ __launch_bounds__(256) void kan_main_kernel(
    const float* __restrict__ x, const float* __restrict__ w,
    float* __restrict__ out) {
  const int lane = threadIdx.x & 63;

  float wreg[36];  // wreg[j] = w[36*lane + j]; dim 4l+i uses wreg[9i..9i+8]
  const float4* w4 = (const float4*)w;
#pragma unroll
  for (int q = 0; q < 9; ++q) {
    float4 v = w4[9 * lane + q];
    wreg[4 * q + 0] = v.x;
    wreg[4 * q + 1] = v.y;
    wreg[4 * q + 2] = v.z;
    wreg[4 * q + 3] = v.w;
  }

  int gw = (int)((blockIdx.x * blockDim.x + threadIdx.x) >> 6);  // global wave id
  int nw = (int)((gridDim.x * blockDim.x) >> 6);                 // total waves

  for (int row = gw; row < B_ROWS; row += nw) {
    const float4* xr = (const float4*)(x + (size_t)row * D_DIM);
    float4 xv = xr[lane];
    float xa[4] = {xv.x, xv.y, xv.z, xv.w};
    float acc = 0.f;
#pragma unroll
    for (int i = 0; i < 4; ++i) {
      // fast tanh: t = 1 - 2/(exp(2x)+1); exact at +-inf, ~1 ulp elsewhere
      float e = __expf(xa[i] + xa[i]);
      float r = __builtin_amdgcn_rcpf(e + 1.f);
      float t = fmaf(-2.f, r, 1.f);
      float t2 = t + t;
      const float* wd = &wreg[9 * i];
      float s    = fmaf(t, wd[1], wd[0]);
      float tkm1 = 1.f, tk = t;
#pragma unroll
      for (int k = 2; k <= DEG; ++k) {
        float tn = fmaf(t2, tk, -tkm1);  // T_{k} = 2x*T_{k-1} - T_{k-2}
        s  = fmaf(tn, wd[k], s);
        tkm1 = tk;
        tk   = tn;
      }
      acc += s;
    }
    // wave-64 butterfly reduce
#pragma unroll
    for (int off = 32; off > 0; off >>= 1)
      acc += __shfl_down(acc, off, 64);
    if (lane == 0) out[row] = acc;
  }
}

extern "C" void kernel_launch(void* const* d_in, const int* in_sizes, int n_in,
                              void* d_out, int out_size, void* d_ws, size_t ws_size,
                              hipStream_t stream) {
  const float* x      = (const float*)d_in[0];  // [32768, 256]
  const float* coeffs = (const float*)d_in[1];  // [256, 2304]
  const float* h      = (const float*)d_in[2];  // [256]
  float* out = (float*)d_out;                   // [32768]
  float* w   = (float*)d_ws;                    // [2304] scratch

  hipMemsetAsync(w, 0, F_FEAT * sizeof(float), stream);
  reduce_w_kernel<<<dim3(F_FEAT / 256, N_NEUR / 16), 256, 0, stream>>>(coeffs, h, w);
  kan_main_kernel<<<2048, 256, 0, stream>>>(x, w, out);
}